// Round 5
// baseline (508.254 us; speedup 1.0000x reference)
//
#include <hip/hip_runtime.h>

typedef unsigned short u16;
typedef __bf16 bf16x8 __attribute__((ext_vector_type(8)));
typedef float f32x4v __attribute__((ext_vector_type(4)));
typedef u16 u16x8 __attribute__((ext_vector_type(8)));

__device__ __forceinline__ u16 f2bf(float f) {
  union { float f; unsigned u; } v; v.f = f;
  unsigned r = v.u + 0x7fffu + ((v.u >> 16) & 1u);  // round-to-nearest-even
  return (u16)(r >> 16);
}
__device__ __forceinline__ float bf2f(u16 h) {
  union { unsigned u; float f; } v; v.u = ((unsigned)h) << 16;
  return v.f;
}

#define G2L16(g, l)                                                            \
  __builtin_amdgcn_global_load_lds((__attribute__((address_space(1))) void*)(g), \
                                   (__attribute__((address_space(3))) void*)(l), 16, 0, 0)

// ---------- merged transpose + fp32->bf16, 64x64 tiles, float4 loads --------
// W1 (2048x4096) -> W1T (4096x2048).
// W2 (4096x2048) -> W2gT (2048x4096) with g1 folded; also emits per-(kblock,n)
// partials of s1 = sum_k g1[k]W2[k][n], c1 = sum_k bt1[k]W2[k][n].
__global__ __launch_bounds__(256) void k_transpose2(const float* __restrict__ W1,
                                                    u16* __restrict__ W1T,
                                                    const float* __restrict__ W2,
                                                    u16* __restrict__ W2gT,
                                                    const float* __restrict__ g1,
                                                    const float* __restrict__ bt1,
                                                    float* __restrict__ w2ps,
                                                    float* __restrict__ w2pc) {
  __shared__ float tile[64][65];
  int bid = blockIdx.x;
  const float* in;
  u16* out;
  int R, C, bx, by, fold;
  if (bid < 2048) {            // W1: 32 row-tiles x 64 col-tiles
    in = W1; out = W1T; R = 2048; C = 4096; fold = 0;
    bx = bid & 63; by = bid >> 6;
  } else {                     // W2: 64 row-tiles x 32 col-tiles
    bid -= 2048;
    in = W2; out = W2gT; R = 4096; C = 2048; fold = 1;
    bx = bid & 31; by = bid >> 5;
  }
  const int c0 = bx * 64, r0 = by * 64;
  const int t = threadIdx.x;
  const int tc = (t & 15) * 4, tr = t >> 4;
#pragma unroll
  for (int i = 0; i < 4; ++i) {
    int r = tr + i * 16;
    f32x4v v = *(const f32x4v*)(in + (size_t)(r0 + r) * C + c0 + tc);
    tile[r][tc] = v[0]; tile[r][tc + 1] = v[1];
    tile[r][tc + 2] = v[2]; tile[r][tc + 3] = v[3];
  }
  __syncthreads();
  const int oc = t >> 2;        // output row (= input col) 0..63
  const int rb = (t & 3) * 16;  // 16 input rows each
  float gv[16];
#pragma unroll
  for (int i = 0; i < 16; ++i) gv[i] = fold ? g1[r0 + rb + i] : 1.f;
  u16x8 o0, o1;
#pragma unroll
  for (int i = 0; i < 8; ++i) o0[i] = f2bf(tile[rb + i][oc] * gv[i]);
#pragma unroll
  for (int i = 0; i < 8; ++i) o1[i] = f2bf(tile[rb + 8 + i][oc] * gv[8 + i]);
  *(u16x8*)(out + (size_t)(c0 + oc) * R + r0 + rb) = o0;
  *(u16x8*)(out + (size_t)(c0 + oc) * R + r0 + rb + 8) = o1;
  if (fold) {
    float ps = 0.f, pc = 0.f;
#pragma unroll
    for (int i = 0; i < 16; ++i) {
      float w = tile[rb + i][oc];
      ps += gv[i] * w;
      pc += bt1[r0 + rb + i] * w;
    }
    ps += __shfl_down(ps, 2, 4); ps += __shfl_down(ps, 1, 4);
    pc += __shfl_down(pc, 2, 4); pc += __shfl_down(pc, 1, 4);
    if ((t & 3) == 0) {
      w2ps[(size_t)by * 2048 + c0 + oc] = ps;
      w2pc[(size_t)by * 2048 + c0 + oc] = pc;
    }
  }
}

// -------- PQ table, split-K=2 into separate partial buffers (no atomics) ----
__global__ __launch_bounds__(256) void k_pq(const float* __restrict__ x1,
                                            const float* __restrict__ We,
                                            float* __restrict__ pq0,
                                            float* __restrict__ pq1) {
  const int n0 = blockIdx.x * 64;
  const int ep = blockIdx.y;  // e*2+p
  const int e = ep >> 1, p = ep & 1;
  const int ks = blockIdx.z * 512;
  float* pq = blockIdx.z ? pq1 : pq0;
  __shared__ float As[64][33];
  __shared__ float Bs[32][68];
  const int t = threadIdx.x;
  const int tx = t & 15, ty = t >> 4;
  float acc[4][4] = {};
  const float* wbase = We + (size_t)e * 2048 * 1024 + (size_t)p * 1024 * 1024;
  for (int k0 = ks; k0 < ks + 512; k0 += 32) {
#pragma unroll
    for (int i = 0; i < 8; ++i) {
      int idx = t + i * 256;
      As[idx >> 5][idx & 31] = x1[(size_t)(idx >> 5) * 1024 + k0 + (idx & 31)];
    }
#pragma unroll
    for (int i = 0; i < 8; ++i) {
      int idx = t + i * 256;
      Bs[idx >> 6][idx & 63] = wbase[(size_t)(k0 + (idx >> 6)) * 1024 + n0 + (idx & 63)];
    }
    __syncthreads();
#pragma unroll
    for (int kk = 0; kk < 32; ++kk) {
      float av[4];
#pragma unroll
      for (int i = 0; i < 4; ++i) av[i] = As[ty * 4 + i][kk];
      f32x4v bv = *(const f32x4v*)&Bs[kk][tx * 4];
#pragma unroll
      for (int i = 0; i < 4; ++i)
#pragma unroll
        for (int j = 0; j < 4; ++j) acc[i][j] += av[i] * bv[j];
    }
    __syncthreads();
  }
#pragma unroll
  for (int i = 0; i < 4; ++i) {
    float* dst = pq + ((size_t)ep * 64 + ty * 4 + i) * 1024 + n0 + tx * 4;
#pragma unroll
    for (int j = 0; j < 4; ++j) dst[j] = acc[i][j];
  }
}

// ---------------- build Y (8192 x 2048, bf16): [relu(P+Q+be) | x2] ----------
__global__ __launch_bounds__(256) void k_build_y(const float* __restrict__ pq0,
                                                 const float* __restrict__ pq1,
                                                 const float* __restrict__ x2,
                                                 const float* __restrict__ be,
                                                 const int* __restrict__ cp,
                                                 const int* __restrict__ vis,
                                                 u16* __restrict__ Y) {
  const int t = threadIdx.x;
  for (int rr = 0; rr < 8; ++rr) {
    const int b = blockIdx.x * 8 + rr;
    const int e = vis[b];
    u16x8 o;
    if (t < 128) {
      const int c0 = cp[2 * b], c1 = cp[2 * b + 1];
      const size_t po = ((size_t)(e * 2) * 64 + c0) * 1024 + t * 8;
      const size_t qo = ((size_t)(e * 2 + 1) * 64 + c1) * 1024 + t * 8;
      const float* B = be + e * 1024 + t * 8;
#pragma unroll
      for (int i = 0; i < 8; ++i) {
        float v = pq0[po + i] + pq1[po + i] + pq0[qo + i] + pq1[qo + i] + B[i];
        o[i] = f2bf(v > 0.f ? v : 0.f);
      }
      *(u16x8*)(Y + (size_t)b * 2048 + t * 8) = o;
    } else {
      const float* X = x2 + (size_t)b * 1024 + (size_t)(t - 128) * 8;
#pragma unroll
      for (int i = 0; i < 8; ++i) o[i] = f2bf(X[i]);
      *(u16x8*)(Y + (size_t)b * 2048 + 1024 + (size_t)(t - 128) * 8) = o;
    }
  }
}

// ---------------- bf16 MFMA GEMM: C(MxN) = epilogue(A(MxK) @ BT(NxK)^T) -----
// 128x128 tile, BK=64, DOUBLE-BUFFERED LDS (one barrier per K-iter, prefetch
// in flight during MFMA), XOR swizzle, XCD supertile.
// MODE 0: relu(acc+bias) + per-row (sum,sumsq) partials for LN1 stats.
// MODE 1: LN1-folded epilogue relu(rs*acc - rs*m*s1[c] + c1b[c]).
#define LOADAB(ASP, BSP)                                                       \
  {                                                                            \
    G2L16(aA, (ASP));                                                          \
    G2L16(aA + (size_t)32 * K, (ASP) + 2048);                                  \
    G2L16(aA + (size_t)64 * K, (ASP) + 4096);                                  \
    G2L16(aA + (size_t)96 * K, (ASP) + 6144);                                  \
    G2L16(bB, (BSP));                                                          \
    G2L16(bB + (size_t)32 * K, (BSP) + 2048);                                  \
    G2L16(bB + (size_t)64 * K, (BSP) + 4096);                                  \
    G2L16(bB + (size_t)96 * K, (BSP) + 6144);                                  \
    aA += 64; bB += 64;                                                        \
  }

#define COMPUTE(ASB, BSB)                                                      \
  {                                                                            \
    bf16x8 af[4], bfr[4];                                                      \
    _Pragma("unroll") for (int mi = 0; mi < 4; ++mi)                           \
        af[mi] = *(const bf16x8*)((ASB) + (am + mi * 16) * 64 + kp0);          \
    _Pragma("unroll") for (int ni = 0; ni < 4; ++ni)                           \
        bfr[ni] = *(const bf16x8*)((BSB) + (bn + ni * 16) * 64 + kp0);         \
    _Pragma("unroll") for (int mi = 0; mi < 4; ++mi)                           \
        _Pragma("unroll") for (int ni = 0; ni < 4; ++ni)                       \
            acc[mi][ni] = __builtin_amdgcn_mfma_f32_16x16x32_bf16(             \
                af[mi], bfr[ni], acc[mi][ni], 0, 0, 0);                        \
    _Pragma("unroll") for (int mi = 0; mi < 4; ++mi)                           \
        af[mi] = *(const bf16x8*)((ASB) + (am + mi * 16) * 64 + kp1);          \
    _Pragma("unroll") for (int ni = 0; ni < 4; ++ni)                           \
        bfr[ni] = *(const bf16x8*)((BSB) + (bn + ni * 16) * 64 + kp1);         \
    _Pragma("unroll") for (int mi = 0; mi < 4; ++mi)                           \
        _Pragma("unroll") for (int ni = 0; ni < 4; ++ni)                       \
            acc[mi][ni] = __builtin_amdgcn_mfma_f32_16x16x32_bf16(             \
                af[mi], bfr[ni], acc[mi][ni], 0, 0, 0);                        \
  }

template <int MODE>
__global__ __launch_bounds__(256) void k_gemm(const u16* __restrict__ A,
                                              const u16* __restrict__ BT,
                                              const float* __restrict__ bias,
                                              const float2* __restrict__ stats,
                                              const float* __restrict__ s1,
                                              const float* __restrict__ c1b,
                                              float2* __restrict__ sp_out,
                                              u16* __restrict__ C, int M, int N, int K) {
  __shared__ u16 As0[128 * 64];   // 16 KB each; two statically distinct
  __shared__ u16 As1[128 * 64];   // buffers so alias analysis can prove
  __shared__ u16 Bs0[128 * 64];   // ds_read(bufX) independent of the
  __shared__ u16 Bs1[128 * 64];   // in-flight global_load_lds(bufY).
  const int tid = threadIdx.x;
  const int lane = tid & 63;
  const int wave = tid >> 6;

  // XCD supertile swizzle (round-robin dispatch: bid%8 = XCD).
  const int nx = gridDim.x, ny = gridDim.y;
  const int bid = blockIdx.y * nx + blockIdx.x;
  const int stripe = ny >> 3;
  const int xcd = bid & 7;
  const int loc = bid >> 3;
  const int panel = loc / (stripe * 4);
  const int rem = loc - panel * (stripe * 4);
  const int by = xcd * stripe + (rem >> 2);
  const int bx = panel * 4 + (rem & 3);
  const int tileN = bx * 128;
  const int tileM = by * 128;
  const int wm = wave & 1;
  const int wn = wave >> 1;

  f32x4v acc[4][4];
#pragma unroll
  for (int i = 0; i < 4; ++i)
#pragma unroll
    for (int j = 0; j < 4; ++j) acc[i][j] = (f32x4v){0.f, 0.f, 0.f, 0.f};

  // Staging: row = tid>>3, physical 16B chunk = tid&7; XOR swizzle
  // phys = (tid&7)^(row&7) (within-row permutation, coalescing intact).
  const int srow = tid >> 3;
  const int lchunk = (tid & 7) ^ (srow & 7);
  const u16* aA = A + (size_t)(tileM + srow) * K + lchunk * 8;
  const u16* bB = BT + (size_t)(tileN + srow) * K + lchunk * 8;
  u16* asp0 = As0 + tid * 8;
  u16* asp1 = As1 + tid * 8;
  u16* bsp0 = Bs0 + tid * 8;
  u16* bsp1 = Bs1 + tid * 8;

  // Fragment reads: row r, logical chunk c at phys c^(r&7); conflict-free.
  const int s = lane & 7;
  const int kp0 = ((lane >> 4) ^ s) * 8;
  const int kp1 = kp0 ^ 32;
  const int am = wm * 64 + (lane & 15);
  const int bn = wn * 64 + (lane & 15);

  const int n = K >> 6;            // K/64 iterations; n is even (32 or 64)
  LOADAB(asp0, bsp0);              // k-chunk 0 -> buf0
  __syncthreads();                 // buf0 ready
  for (int it = 0; it < n; it += 2) {
    LOADAB(asp1, bsp1);            // prefetch it+1 -> buf1 (in flight below)
    COMPUTE(As0, Bs0);
    __syncthreads();               // readers of buf0 done; drains prefetch
    if (it + 2 < n) LOADAB(asp0, bsp0);  // prefetch it+2 -> buf0
    COMPUTE(As1, Bs1);
    __syncthreads();
  }

  // C/D layout (m89-verified): col = lane&15, row = (lane>>4)*4 + reg
  const int crow = tileM + wm * 64 + (lane >> 4) * 4;
  const int ccol = tileN + wn * 64 + (lane & 15);
  float cv0[4], cv1[4];
#pragma unroll
  for (int ni = 0; ni < 4; ++ni) {
    const int c = ccol + ni * 16;
    if (MODE == 0) {
      cv0[ni] = bias[c];
    } else {
      cv0[ni] = s1[c];
      cv1[ni] = c1b[c];
    }
  }
  const int cb = bx * 2 + wn;      // 64-col block index for stats partials
#pragma unroll
  for (int mi = 0; mi < 4; ++mi) {
#pragma unroll
    for (int r = 0; r < 4; ++r) {
      const int row = crow + mi * 16 + r;
      float m = 0.f, rs = 0.f;
      if (MODE == 1) {
        float2 st = stats[row];
        m = st.x; rs = st.y;
      }
      float s_ = 0.f, ss_ = 0.f;
#pragma unroll
      for (int ni = 0; ni < 4; ++ni) {
        float v;
        if (MODE == 0)
          v = acc[mi][ni][r] + cv0[ni];
        else
          v = rs * acc[mi][ni][r] - rs * m * cv0[ni] + cv1[ni];
        v = v > 0.f ? v : 0.f;
        if (MODE == 0) { s_ += v; ss_ += v * v; }
        C[(size_t)row * N + ccol + ni * 16] = f2bf(v);
      }
      if (MODE == 0) {
        // reduce over the 16 lanes sharing this row (lane&15 = col id)
#pragma unroll
        for (int off = 8; off >= 1; off >>= 1) {
          s_ += __shfl_xor(s_, off, 16);
          ss_ += __shfl_xor(ss_, off, 16);
        }
        if ((lane & 15) == 0)
          sp_out[(size_t)cb * 8192 + row] = make_float2(s_, ss_);
      }
    }
  }
}

// ---- reduce: LN1 stats from GEMM1 partials; s1/c1b from transpose partials -
__global__ __launch_bounds__(256) void k_reduce(const float2* __restrict__ sp,
                                                float2* __restrict__ stats,
                                                const float* __restrict__ w2ps,
                                                const float* __restrict__ w2pc,
                                                const float* __restrict__ b2,
                                                float* __restrict__ s1,
                                                float* __restrict__ c1b) {
  const int bid = blockIdx.x;
  if (bid < 32) {
    const int row = bid * 256 + threadIdx.x;
    float s = 0.f, ss = 0.f;
    for (int cbk = 0; cbk < 64; ++cbk) {
      float2 p = sp[(size_t)cbk * 8192 + row];
      s += p.x; ss += p.y;
    }
    float m = s * (1.f / 4096.f);
    float var = ss * (1.f / 4096.f) - m * m;
    stats[row] = make_float2(m, rsqrtf(var + 1e-5f));
  } else {
    const int nn = (bid - 32) * 256 + threadIdx.x;
    float s = 0.f, c = 0.f;
    for (int kb = 0; kb < 64; ++kb) {
      s += w2ps[(size_t)kb * 2048 + nn];
      c += w2pc[(size_t)kb * 2048 + nn];
    }
    s1[nn] = s;
    c1b[nn] = c + b2[nn];
  }
}

// ------- fused LN2 + final, one wave per row, no LDS ------------------------
__global__ __launch_bounds__(256) void k_ln_final(const u16* __restrict__ H2,
                                                  const float* __restrict__ g,
                                                  const float* __restrict__ bt,
                                                  const float* __restrict__ W3,
                                                  const float* __restrict__ b3,
                                                  float* __restrict__ out) {
  const int lane = threadIdx.x & 63;
  const int b = blockIdx.x * 4 + (threadIdx.x >> 6);
  const u16* row = H2 + (size_t)b * 2048;
  float vals[4][8];
  float s = 0.f, ss = 0.f;
#pragma unroll
  for (int c = 0; c < 4; ++c) {
    u16x8 v = *(const u16x8*)(row + c * 512 + lane * 8);
#pragma unroll
    for (int i = 0; i < 8; ++i) {
      float f = bf2f(v[i]);
      vals[c][i] = f;
      s += f;
      ss += f * f;
    }
  }
#pragma unroll
  for (int off = 32; off > 0; off >>= 1) {
    s += __shfl_down(s, off, 64);
    ss += __shfl_down(ss, off, 64);
  }
  s = __shfl(s, 0);
  ss = __shfl(ss, 0);
  const float m = s * (1.f / 2048.f);
  const float rs = rsqrtf(ss * (1.f / 2048.f) - m * m + 1e-5f);
  float dot = 0.f;
#pragma unroll
  for (int c = 0; c < 4; ++c)
#pragma unroll
    for (int i = 0; i < 8; ++i) {
      int col = c * 512 + lane * 8 + i;
      float h = (vals[c][i] - m) * rs * g[col] + bt[col];
      dot += h * W3[col];
    }
#pragma unroll
  for (int off = 32; off > 0; off >>= 1) dot += __shfl_down(dot, off, 64);
  if (lane == 0) out[b] = 1.f / (1.f + expf(-(dot + b3[0])));
}

extern "C" void kernel_launch(void* const* d_in, const int* in_sizes, int n_in,
                              void* d_out, int out_size, void* d_ws, size_t ws_size,
                              hipStream_t stream) {
  const float* x1 = (const float*)d_in[0];
  const float* x2 = (const float*)d_in[1];
  const float* We = (const float*)d_in[2];
  const float* be = (const float*)d_in[3];
  const float* W1 = (const float*)d_in[4];
  const float* b1 = (const float*)d_in[5];
  const float* g1 = (const float*)d_in[6];
  const float* bt1 = (const float*)d_in[7];
  const float* W2 = (const float*)d_in[8];
  const float* b2 = (const float*)d_in[9];
  const float* g2 = (const float*)d_in[10];
  const float* bt2 = (const float*)d_in[11];
  const float* W3 = (const float*)d_in[12];
  const float* b3 = (const float*)d_in[13];
  const int* cp = (const int*)d_in[14];
  const int* vis = (const int*)d_in[15];
  float* out = (float*)d_out;

  char* ws = (char*)d_ws;
  u16* W1T  = (u16*)(ws);                  // 4096x2048 bf16 = 16 MiB
  u16* W2gT = (u16*)(ws + 16777216);       // 2048x4096 bf16 = 16 MiB
  u16* Y    = (u16*)(ws + 33554432);       // 8192x2048 bf16 = 32 MiB (reused as H2)
  u16* H1   = (u16*)(ws + 67108864);       // 8192x4096 bf16 = 64 MiB
  float* PQ0 = (float*)(ws + 134217728);   // 2 MiB
  float* PQ1 = (float*)(ws + 136314880);   // 2 MiB
  // sp (LN1 stats partials, 8192x64 float2 = 4 MiB) REUSES PQ0+PQ1: PQ is
  // dead after k_build_y, sp written by k_gemm<0> afterwards.
  float2* sp = (float2*)(ws + 134217728);
  float2* stats = (float2*)(ws + 138412032);  // 64 KiB
  float* s1   = (float*)(ws + 138477568);     // 8 KiB
  float* c1b  = (float*)(ws + 138485760);     // 8 KiB
  float* w2ps = (float*)(ws + 138493952);     // 64x2048 f32 = 512 KiB
  float* w2pc = (float*)(ws + 139018240);     // 512 KiB (ends ~133.1 MiB)
  u16* H2 = Y;

  k_transpose2<<<4096, 256, 0, stream>>>(W1, W1T, W2, W2gT, g1, bt1, w2ps, w2pc);
  k_pq<<<dim3(16, 8, 2), 256, 0, stream>>>(x1, We, PQ0, PQ1);
  k_build_y<<<1024, 256, 0, stream>>>(PQ0, PQ1, x2, be, cp, vis, Y);
  k_gemm<0><<<dim3(32, 64), 256, 0, stream>>>(
      Y, W1T, b1, nullptr, nullptr, nullptr, sp, H1, 8192, 4096, 2048);
  k_reduce<<<40, 256, 0, stream>>>(sp, stats, w2ps, w2pc, b2, s1, c1b);
  k_gemm<1><<<dim3(16, 64), 256, 0, stream>>>(
      H1, W2gT, nullptr, stats, s1, c1b, nullptr, H2, 8192, 2048, 4096);
  k_ln_final<<<2048, 256, 0, stream>>>(H2, g2, bt2, W3, b3, out);
}

// Round 6
// 497.647 us; speedup vs baseline: 1.0213x; 1.0213x over previous
//
#include <hip/hip_runtime.h>

typedef unsigned short u16;
typedef __bf16 bf16x8 __attribute__((ext_vector_type(8)));
typedef float f32x4v __attribute__((ext_vector_type(4)));
typedef u16 u16x8 __attribute__((ext_vector_type(8)));

__device__ __forceinline__ u16 f2bf(float f) {
  union { float f; unsigned u; } v; v.f = f;
  unsigned r = v.u + 0x7fffu + ((v.u >> 16) & 1u);  // round-to-nearest-even
  return (u16)(r >> 16);
}
__device__ __forceinline__ float bf2f(u16 h) {
  union { unsigned u; float f; } v; v.u = ((unsigned)h) << 16;
  return v.f;
}

#define G2L16(g, l)                                                            \
  __builtin_amdgcn_global_load_lds((__attribute__((address_space(1))) void*)(g), \
                                   (__attribute__((address_space(3))) void*)(l), 16, 0, 0)

// ---------- merged pre-pass: W1/W2 transpose+cast AND PQ table --------------
// bid < 4096 : transpose tiles. W1 (2048x4096)->W1T (4096x2048);
//              W2 (4096x2048)->W2gT (2048x4096) with g1 folded + s1/c1 partials.
// bid >= 4096: PQ: pqz[(e*2+p)][c][n] = sum_{k half z} x1[c][k]*We[e][p*1024+k][n]
__global__ __launch_bounds__(256) void k_pre(const float* __restrict__ W1,
                                             u16* __restrict__ W1T,
                                             const float* __restrict__ W2,
                                             u16* __restrict__ W2gT,
                                             const float* __restrict__ g1,
                                             const float* __restrict__ bt1,
                                             float* __restrict__ w2ps,
                                             float* __restrict__ w2pc,
                                             const float* __restrict__ x1,
                                             const float* __restrict__ We,
                                             float* __restrict__ pq0,
                                             float* __restrict__ pq1) {
  __shared__ char smem[17536];  // union: tile 64x65 f32 (16.25KB) | As+Bs (17.1KB)
  const int t = threadIdx.x;
  int bid = blockIdx.x;
  if (bid < 4096) {
    float(*tile)[65] = (float(*)[65])smem;
    const float* in;
    u16* out;
    int R, C, bx, by, fold;
    if (bid < 2048) {            // W1: 32 row-tiles x 64 col-tiles
      in = W1; out = W1T; R = 2048; C = 4096; fold = 0;
      bx = bid & 63; by = bid >> 6;
    } else {                     // W2: 64 row-tiles x 32 col-tiles
      bid -= 2048;
      in = W2; out = W2gT; R = 4096; C = 2048; fold = 1;
      bx = bid & 31; by = bid >> 5;
    }
    const int c0 = bx * 64, r0 = by * 64;
    const int tc = (t & 15) * 4, tr = t >> 4;
#pragma unroll
    for (int i = 0; i < 4; ++i) {
      int r = tr + i * 16;
      f32x4v v = *(const f32x4v*)(in + (size_t)(r0 + r) * C + c0 + tc);
      tile[r][tc] = v[0]; tile[r][tc + 1] = v[1];
      tile[r][tc + 2] = v[2]; tile[r][tc + 3] = v[3];
    }
    __syncthreads();
    const int oc = t >> 2;        // output row (= input col) 0..63
    const int rb = (t & 3) * 16;  // 16 input rows each
    float gv[16];
#pragma unroll
    for (int i = 0; i < 16; ++i) gv[i] = fold ? g1[r0 + rb + i] : 1.f;
    u16x8 o0, o1;
#pragma unroll
    for (int i = 0; i < 8; ++i) o0[i] = f2bf(tile[rb + i][oc] * gv[i]);
#pragma unroll
    for (int i = 0; i < 8; ++i) o1[i] = f2bf(tile[rb + 8 + i][oc] * gv[8 + i]);
    *(u16x8*)(out + (size_t)(c0 + oc) * R + r0 + rb) = o0;
    *(u16x8*)(out + (size_t)(c0 + oc) * R + r0 + rb + 8) = o1;
    if (fold) {
      float ps = 0.f, pc = 0.f;
#pragma unroll
      for (int i = 0; i < 16; ++i) {
        float w = tile[rb + i][oc];
        ps += gv[i] * w;
        pc += bt1[r0 + rb + i] * w;
      }
      ps += __shfl_down(ps, 2, 4); ps += __shfl_down(ps, 1, 4);
      pc += __shfl_down(pc, 2, 4); pc += __shfl_down(pc, 1, 4);
      if ((t & 3) == 0) {
        w2ps[(size_t)by * 2048 + c0 + oc] = ps;
        w2pc[(size_t)by * 2048 + c0 + oc] = pc;
      }
    }
  } else {
    // ---- PQ part ----
    const int idx = bid - 4096;          // 0..255
    const int n0 = (idx & 15) * 64;
    const int ep = (idx >> 4) & 7;
    const int e = ep >> 1, p = ep & 1;
    const int z = idx >> 7;
    const int ks = z * 512;
    float* pq = z ? pq1 : pq0;
    float(*As)[33] = (float(*)[33])smem;             // 64x33
    float(*Bs)[68] = (float(*)[68])(smem + 8448);    // 32x68
    const int tx = t & 15, ty = t >> 4;
    float acc[4][4] = {};
    const float* wbase = We + (size_t)e * 2048 * 1024 + (size_t)p * 1024 * 1024;
    for (int k0 = ks; k0 < ks + 512; k0 += 32) {
#pragma unroll
      for (int i = 0; i < 8; ++i) {
        int ix = t + i * 256;
        As[ix >> 5][ix & 31] = x1[(size_t)(ix >> 5) * 1024 + k0 + (ix & 31)];
      }
#pragma unroll
      for (int i = 0; i < 8; ++i) {
        int ix = t + i * 256;
        Bs[ix >> 6][ix & 63] = wbase[(size_t)(k0 + (ix >> 6)) * 1024 + n0 + (ix & 63)];
      }
      __syncthreads();
#pragma unroll
      for (int kk = 0; kk < 32; ++kk) {
        float av[4];
#pragma unroll
        for (int i = 0; i < 4; ++i) av[i] = As[ty * 4 + i][kk];
        f32x4v bv = *(const f32x4v*)&Bs[kk][tx * 4];
#pragma unroll
        for (int i = 0; i < 4; ++i)
#pragma unroll
          for (int j = 0; j < 4; ++j) acc[i][j] += av[i] * bv[j];
      }
      __syncthreads();
    }
#pragma unroll
    for (int i = 0; i < 4; ++i) {
      float* dst = pq + ((size_t)ep * 64 + ty * 4 + i) * 1024 + n0 + tx * 4;
#pragma unroll
      for (int j = 0; j < 4; ++j) dst[j] = acc[i][j];
    }
  }
}

// ---------------- build Y (8192 x 2048, bf16): [relu(P+Q+be) | x2] ----------
__global__ __launch_bounds__(256) void k_build_y(const float* __restrict__ pq0,
                                                 const float* __restrict__ pq1,
                                                 const float* __restrict__ x2,
                                                 const float* __restrict__ be,
                                                 const int* __restrict__ cp,
                                                 const int* __restrict__ vis,
                                                 u16* __restrict__ Y) {
  const int t = threadIdx.x;
  for (int rr = 0; rr < 8; ++rr) {
    const int b = blockIdx.x * 8 + rr;
    const int e = vis[b];
    u16x8 o;
    if (t < 128) {
      const int c0 = cp[2 * b], c1 = cp[2 * b + 1];
      const size_t po = ((size_t)(e * 2) * 64 + c0) * 1024 + t * 8;
      const size_t qo = ((size_t)(e * 2 + 1) * 64 + c1) * 1024 + t * 8;
      const float* B = be + e * 1024 + t * 8;
#pragma unroll
      for (int i = 0; i < 8; ++i) {
        float v = pq0[po + i] + pq1[po + i] + pq0[qo + i] + pq1[qo + i] + B[i];
        o[i] = f2bf(v > 0.f ? v : 0.f);
      }
      *(u16x8*)(Y + (size_t)b * 2048 + t * 8) = o;
    } else {
      const float* X = x2 + (size_t)b * 1024 + (size_t)(t - 128) * 8;
#pragma unroll
      for (int i = 0; i < 8; ++i) o[i] = f2bf(X[i]);
      *(u16x8*)(Y + (size_t)b * 2048 + 1024 + (size_t)(t - 128) * 8) = o;
    }
  }
}

// ---------------- bf16 MFMA GEMM: C(MxN) = epilogue(A(MxK) @ BT(NxK)^T) -----
// Round-3 structure: 128x128 tile, BK=64 single-buffer (32 MFMA per barrier
// pair, 3 blocks/CU inter-block overlap), XOR swizzle, XCD supertile.
// MODE 0: relu(acc+bias) + per-row (sum,sumsq) partials for LN1 stats.
// MODE 1: LN1-folded epilogue relu(rs*acc - rs*m*s1[c] + c1b[c]).
template <int MODE>
__global__ __launch_bounds__(256, 3) void k_gemm(const u16* __restrict__ A,
                                                 const u16* __restrict__ BT,
                                                 const float* __restrict__ bias,
                                                 const float2* __restrict__ stats,
                                                 const float* __restrict__ s1,
                                                 const float* __restrict__ c1b,
                                                 float2* __restrict__ sp_out,
                                                 u16* __restrict__ C, int M, int N, int K) {
  __shared__ u16 As[128 * 64];   // 16 KB
  __shared__ u16 Bs[128 * 64];   // 16 KB
  const int tid = threadIdx.x;
  const int lane = tid & 63;
  const int wave = tid >> 6;

  // XCD supertile swizzle (round-robin dispatch: bid%8 = XCD).
  const int nx = gridDim.x, ny = gridDim.y;
  const int bid = blockIdx.y * nx + blockIdx.x;
  const int stripe = ny >> 3;
  const int xcd = bid & 7;
  const int loc = bid >> 3;
  const int panel = loc / (stripe * 4);
  const int rem = loc - panel * (stripe * 4);
  const int by = xcd * stripe + (rem >> 2);
  const int bx = panel * 4 + (rem & 3);
  const int tileN = bx * 128;
  const int tileM = by * 128;
  const int wm = wave & 1;
  const int wn = wave >> 1;

  f32x4v acc[4][4];
#pragma unroll
  for (int i = 0; i < 4; ++i)
#pragma unroll
    for (int j = 0; j < 4; ++j) acc[i][j] = (f32x4v){0.f, 0.f, 0.f, 0.f};

  // Staging: row = tid>>3 (0..31), physical 16B chunk = tid&7.
  // XOR swizzle: phys chunk holds logical chunk (tid&7)^(row&7).
  const int srow = tid >> 3;
  const int lchunk = (tid & 7) ^ (srow & 7);
  const u16* aptr = A + (size_t)(tileM + srow) * K + lchunk * 8;
  const u16* bptr = BT + (size_t)(tileN + srow) * K + lchunk * 8;
  u16* asp = As + tid * 8;
  u16* bsp = Bs + tid * 8;

  // Fragment reads: row r, logical chunk c at phys c^(r&7); conflict-free.
  const int s = lane & 7;
  const int kp0 = ((lane >> 4) ^ s) * 8;
  const int kp1 = kp0 ^ 32;
  const int am = wm * 64 + (lane & 15);
  const int bn = wn * 64 + (lane & 15);

  for (int k0 = 0; k0 < K; k0 += 64) {
    G2L16(aptr, asp);
    G2L16(aptr + (size_t)32 * K, asp + 2048);
    G2L16(aptr + (size_t)64 * K, asp + 4096);
    G2L16(aptr + (size_t)96 * K, asp + 6144);
    G2L16(bptr, bsp);
    G2L16(bptr + (size_t)32 * K, bsp + 2048);
    G2L16(bptr + (size_t)64 * K, bsp + 4096);
    G2L16(bptr + (size_t)96 * K, bsp + 6144);
    aptr += 64;
    bptr += 64;
    __syncthreads();

    bf16x8 af[4], bfr[4];
#pragma unroll
    for (int mi = 0; mi < 4; ++mi)
      af[mi] = *(const bf16x8*)(As + (am + mi * 16) * 64 + kp0);
#pragma unroll
    for (int ni = 0; ni < 4; ++ni)
      bfr[ni] = *(const bf16x8*)(Bs + (bn + ni * 16) * 64 + kp0);
#pragma unroll
    for (int mi = 0; mi < 4; ++mi)
#pragma unroll
      for (int ni = 0; ni < 4; ++ni)
        acc[mi][ni] = __builtin_amdgcn_mfma_f32_16x16x32_bf16(af[mi], bfr[ni], acc[mi][ni], 0, 0, 0);
#pragma unroll
    for (int mi = 0; mi < 4; ++mi)
      af[mi] = *(const bf16x8*)(As + (am + mi * 16) * 64 + kp1);
#pragma unroll
    for (int ni = 0; ni < 4; ++ni)
      bfr[ni] = *(const bf16x8*)(Bs + (bn + ni * 16) * 64 + kp1);
#pragma unroll
    for (int mi = 0; mi < 4; ++mi)
#pragma unroll
      for (int ni = 0; ni < 4; ++ni)
        acc[mi][ni] = __builtin_amdgcn_mfma_f32_16x16x32_bf16(af[mi], bfr[ni], acc[mi][ni], 0, 0, 0);
    __syncthreads();
  }

  // C/D layout (m89-verified): col = lane&15, row = (lane>>4)*4 + reg
  const int crow = tileM + wm * 64 + (lane >> 4) * 4;
  const int ccol = tileN + wn * 64 + (lane & 15);
  float cv0[4], cv1[4];
#pragma unroll
  for (int ni = 0; ni < 4; ++ni) {
    const int c = ccol + ni * 16;
    if (MODE == 0) {
      cv0[ni] = bias[c];
    } else {
      cv0[ni] = s1[c];
      cv1[ni] = c1b[c];
    }
  }
  const int cb = bx * 2 + wn;      // 64-col block index for stats partials
#pragma unroll
  for (int mi = 0; mi < 4; ++mi) {
#pragma unroll
    for (int r = 0; r < 4; ++r) {
      const int row = crow + mi * 16 + r;
      float m = 0.f, rs = 0.f;
      if (MODE == 1) {
        float2 st = stats[row];
        m = st.x; rs = st.y;
      }
      float s_ = 0.f, ss_ = 0.f;
#pragma unroll
      for (int ni = 0; ni < 4; ++ni) {
        float v;
        if (MODE == 0)
          v = acc[mi][ni][r] + cv0[ni];
        else
          v = rs * acc[mi][ni][r] - rs * m * cv0[ni] + cv1[ni];
        v = v > 0.f ? v : 0.f;
        if (MODE == 0) { s_ += v; ss_ += v * v; }
        C[(size_t)row * N + ccol + ni * 16] = f2bf(v);
      }
      if (MODE == 0) {
        // reduce over the 16 lanes sharing this row (lane&15 = col id)
#pragma unroll
        for (int off = 8; off >= 1; off >>= 1) {
          s_ += __shfl_xor(s_, off, 16);
          ss_ += __shfl_xor(ss_, off, 16);
        }
        if ((lane & 15) == 0)
          sp_out[(size_t)cb * 8192 + row] = make_float2(s_, ss_);
      }
    }
  }
}

// ---- reduce: LN1 stats from GEMM1 partials; s1/c1b from transpose partials -
__global__ __launch_bounds__(256) void k_reduce(const float2* __restrict__ sp,
                                                float2* __restrict__ stats,
                                                const float* __restrict__ w2ps,
                                                const float* __restrict__ w2pc,
                                                const float* __restrict__ b2,
                                                float* __restrict__ s1,
                                                float* __restrict__ c1b) {
  const int bid = blockIdx.x;
  if (bid < 32) {
    const int row = bid * 256 + threadIdx.x;
    float s = 0.f, ss = 0.f;
    for (int cbk = 0; cbk < 64; ++cbk) {
      float2 p = sp[(size_t)cbk * 8192 + row];
      s += p.x; ss += p.y;
    }
    float m = s * (1.f / 4096.f);
    float var = ss * (1.f / 4096.f) - m * m;
    stats[row] = make_float2(m, rsqrtf(var + 1e-5f));
  } else {
    const int nn = (bid - 32) * 256 + threadIdx.x;
    float s = 0.f, c = 0.f;
    for (int kb = 0; kb < 64; ++kb) {
      s += w2ps[(size_t)kb * 2048 + nn];
      c += w2pc[(size_t)kb * 2048 + nn];
    }
    s1[nn] = s;
    c1b[nn] = c + b2[nn];
  }
}

// ------- fused LN2 + final, one wave per row, no LDS ------------------------
__global__ __launch_bounds__(256) void k_ln_final(const u16* __restrict__ H2,
                                                  const float* __restrict__ g,
                                                  const float* __restrict__ bt,
                                                  const float* __restrict__ W3,
                                                  const float* __restrict__ b3,
                                                  float* __restrict__ out) {
  const int lane = threadIdx.x & 63;
  const int b = blockIdx.x * 4 + (threadIdx.x >> 6);
  const u16* row = H2 + (size_t)b * 2048;
  float vals[4][8];
  float s = 0.f, ss = 0.f;
#pragma unroll
  for (int c = 0; c < 4; ++c) {
    u16x8 v = *(const u16x8*)(row + c * 512 + lane * 8);
#pragma unroll
    for (int i = 0; i < 8; ++i) {
      float f = bf2f(v[i]);
      vals[c][i] = f;
      s += f;
      ss += f * f;
    }
  }
#pragma unroll
  for (int off = 32; off > 0; off >>= 1) {
    s += __shfl_down(s, off, 64);
    ss += __shfl_down(ss, off, 64);
  }
  s = __shfl(s, 0);
  ss = __shfl(ss, 0);
  const float m = s * (1.f / 2048.f);
  const float rs = rsqrtf(ss * (1.f / 2048.f) - m * m + 1e-5f);
  float dot = 0.f;
#pragma unroll
  for (int c = 0; c < 4; ++c)
#pragma unroll
    for (int i = 0; i < 8; ++i) {
      int col = c * 512 + lane * 8 + i;
      float h = (vals[c][i] - m) * rs * g[col] + bt[col];
      dot += h * W3[col];
    }
#pragma unroll
  for (int off = 32; off > 0; off >>= 1) dot += __shfl_down(dot, off, 64);
  if (lane == 0) out[b] = 1.f / (1.f + expf(-(dot + b3[0])));
}

extern "C" void kernel_launch(void* const* d_in, const int* in_sizes, int n_in,
                              void* d_out, int out_size, void* d_ws, size_t ws_size,
                              hipStream_t stream) {
  const float* x1 = (const float*)d_in[0];
  const float* x2 = (const float*)d_in[1];
  const float* We = (const float*)d_in[2];
  const float* be = (const float*)d_in[3];
  const float* W1 = (const float*)d_in[4];
  const float* b1 = (const float*)d_in[5];
  const float* g1 = (const float*)d_in[6];
  const float* bt1 = (const float*)d_in[7];
  const float* W2 = (const float*)d_in[8];
  const float* b2 = (const float*)d_in[9];
  const float* g2 = (const float*)d_in[10];
  const float* bt2 = (const float*)d_in[11];
  const float* W3 = (const float*)d_in[12];
  const float* b3 = (const float*)d_in[13];
  const int* cp = (const int*)d_in[14];
  const int* vis = (const int*)d_in[15];
  float* out = (float*)d_out;

  char* ws = (char*)d_ws;
  u16* W1T  = (u16*)(ws);                  // 4096x2048 bf16 = 16 MiB
  u16* W2gT = (u16*)(ws + 16777216);       // 2048x4096 bf16 = 16 MiB
  u16* Y    = (u16*)(ws + 33554432);       // 8192x2048 bf16 = 32 MiB (reused as H2)
  u16* H1   = (u16*)(ws + 67108864);       // 8192x4096 bf16 = 64 MiB
  float* PQ0 = (float*)(ws + 134217728);   // 2 MiB
  float* PQ1 = (float*)(ws + 136314880);   // 2 MiB
  // sp (LN1 stats partials, 64x8192 float2 = 4 MiB) REUSES PQ0+PQ1: PQ is
  // dead after k_build_y, sp written by k_gemm<0> afterwards.
  float2* sp = (float2*)(ws + 134217728);
  float2* stats = (float2*)(ws + 138412032);  // 64 KiB
  float* s1   = (float*)(ws + 138477568);     // 8 KiB
  float* c1b  = (float*)(ws + 138485760);     // 8 KiB
  float* w2ps = (float*)(ws + 138493952);     // 64x2048 f32 = 512 KiB
  float* w2pc = (float*)(ws + 139018240);     // 512 KiB (ends ~133.1 MiB)
  u16* H2 = Y;

  k_pre<<<4352, 256, 0, stream>>>(W1, W1T, W2, W2gT, g1, bt1, w2ps, w2pc,
                                  x1, We, PQ0, PQ1);
  k_build_y<<<1024, 256, 0, stream>>>(PQ0, PQ1, x2, be, cp, vis, Y);
  k_gemm<0><<<dim3(32, 64), 256, 0, stream>>>(
      Y, W1T, b1, nullptr, nullptr, nullptr, sp, H1, 8192, 4096, 2048);
  k_reduce<<<40, 256, 0, stream>>>(sp, stats, w2ps, w2pc, b2, s1, c1b);
  k_gemm<1><<<dim3(16, 64), 256, 0, stream>>>(
      H1, W2gT, nullptr, stats, s1, c1b, nullptr, H2, 8192, 2048, 4096);
  k_ln_final<<<2048, 256, 0, stream>>>(H2, g2, bt2, W3, b3, out);
}

// Round 7
// 474.760 us; speedup vs baseline: 1.0706x; 1.0482x over previous
//
#include <hip/hip_runtime.h>

typedef unsigned short u16;
typedef __bf16 bf16x8 __attribute__((ext_vector_type(8)));
typedef float f32x4v __attribute__((ext_vector_type(4)));
typedef u16 u16x8 __attribute__((ext_vector_type(8)));

__device__ __forceinline__ u16 f2bf(float f) {
  union { float f; unsigned u; } v; v.f = f;
  unsigned r = v.u + 0x7fffu + ((v.u >> 16) & 1u);  // round-to-nearest-even
  return (u16)(r >> 16);
}
__device__ __forceinline__ float bf2f(u16 h) {
  union { unsigned u; float f; } v; v.u = ((unsigned)h) << 16;
  return v.f;
}

#define G2L16(g, l)                                                            \
  __builtin_amdgcn_global_load_lds((__attribute__((address_space(1))) void*)(g), \
                                   (__attribute__((address_space(3))) void*)(l), 16, 0, 0)

// ---------- transpose + fp32->bf16, 64x64 tiles, float4 loads ---------------
// W1 (2048x4096) -> W1T (4096x2048); W2 (4096x2048) -> W2gT (2048x4096) with
// g1 folded; also per-(kblock,n) partials of s1=sum g1*W2, c1=sum bt1*W2.
__global__ __launch_bounds__(256) void k_transpose2(const float* __restrict__ W1,
                                                    u16* __restrict__ W1T,
                                                    const float* __restrict__ W2,
                                                    u16* __restrict__ W2gT,
                                                    const float* __restrict__ g1,
                                                    const float* __restrict__ bt1,
                                                    float* __restrict__ w2ps,
                                                    float* __restrict__ w2pc) {
  __shared__ float tile[64][65];
  int bid = blockIdx.x;
  const float* in;
  u16* out;
  int R, C, bx, by, fold;
  if (bid < 2048) {            // W1: 32 row-tiles x 64 col-tiles
    in = W1; out = W1T; R = 2048; C = 4096; fold = 0;
    bx = bid & 63; by = bid >> 6;
  } else {                     // W2: 64 row-tiles x 32 col-tiles
    bid -= 2048;
    in = W2; out = W2gT; R = 4096; C = 2048; fold = 1;
    bx = bid & 31; by = bid >> 5;
  }
  const int c0 = bx * 64, r0 = by * 64;
  const int t = threadIdx.x;
  const int tc = (t & 15) * 4, tr = t >> 4;
#pragma unroll
  for (int i = 0; i < 4; ++i) {
    int r = tr + i * 16;
    f32x4v v = *(const f32x4v*)(in + (size_t)(r0 + r) * C + c0 + tc);
    tile[r][tc] = v[0]; tile[r][tc + 1] = v[1];
    tile[r][tc + 2] = v[2]; tile[r][tc + 3] = v[3];
  }
  __syncthreads();
  const int oc = t >> 2;        // output row (= input col) 0..63
  const int rb = (t & 3) * 16;  // 16 input rows each
  float gv[16];
#pragma unroll
  for (int i = 0; i < 16; ++i) gv[i] = fold ? g1[r0 + rb + i] : 1.f;
  u16x8 o0, o1;
#pragma unroll
  for (int i = 0; i < 8; ++i) o0[i] = f2bf(tile[rb + i][oc] * gv[i]);
#pragma unroll
  for (int i = 0; i < 8; ++i) o1[i] = f2bf(tile[rb + 8 + i][oc] * gv[8 + i]);
  *(u16x8*)(out + (size_t)(c0 + oc) * R + r0 + rb) = o0;
  *(u16x8*)(out + (size_t)(c0 + oc) * R + r0 + rb + 8) = o1;
  if (fold) {
    float ps = 0.f, pc = 0.f;
#pragma unroll
    for (int i = 0; i < 16; ++i) {
      float w = tile[rb + i][oc];
      ps += gv[i] * w;
      pc += bt1[r0 + rb + i] * w;
    }
    ps += __shfl_down(ps, 2, 4); ps += __shfl_down(ps, 1, 4);
    pc += __shfl_down(pc, 2, 4); pc += __shfl_down(pc, 1, 4);
    if ((t & 3) == 0) {
      w2ps[(size_t)by * 2048 + c0 + oc] = ps;
      w2pc[(size_t)by * 2048 + c0 + oc] = pc;
    }
  }
}

// -------- PQ table, split over (khalf, chalf): 512 blocks, no atomics -------
// pq{z}[(e*2+p)][c][n] = sum_{k in half z} x1[c][k] * We[e][p*1024+k][n]
__global__ __launch_bounds__(256) void k_pq(const float* __restrict__ x1,
                                            const float* __restrict__ We,
                                            float* __restrict__ pq0,
                                            float* __restrict__ pq1) {
  const int n0 = blockIdx.x * 64;
  const int ep = blockIdx.y;  // e*2+p
  const int e = ep >> 1, p = ep & 1;
  const int khalf = blockIdx.z & 1;
  const int chalf = blockIdx.z >> 1;
  const int ks = khalf * 512;
  float* pq = khalf ? pq1 : pq0;
  __shared__ float As[32][33];
  __shared__ float Bs[32][68];
  const int t = threadIdx.x;
  const int tx = t & 15, ty = t >> 4;
  float acc[2][4] = {};
  const float* wbase = We + (size_t)e * 2048 * 1024 + (size_t)p * 1024 * 1024;
  for (int k0 = ks; k0 < ks + 512; k0 += 32) {
#pragma unroll
    for (int i = 0; i < 4; ++i) {
      int ix = t + i * 256;
      As[ix >> 5][ix & 31] =
          x1[(size_t)(chalf * 32 + (ix >> 5)) * 1024 + k0 + (ix & 31)];
    }
#pragma unroll
    for (int i = 0; i < 8; ++i) {
      int ix = t + i * 256;
      Bs[ix >> 6][ix & 63] = wbase[(size_t)(k0 + (ix >> 6)) * 1024 + n0 + (ix & 63)];
    }
    __syncthreads();
#pragma unroll
    for (int kk = 0; kk < 32; ++kk) {
      float av[2];
#pragma unroll
      for (int i = 0; i < 2; ++i) av[i] = As[ty * 2 + i][kk];
      f32x4v bv = *(const f32x4v*)&Bs[kk][tx * 4];
#pragma unroll
      for (int i = 0; i < 2; ++i)
#pragma unroll
        for (int j = 0; j < 4; ++j) acc[i][j] += av[i] * bv[j];
    }
    __syncthreads();
  }
#pragma unroll
  for (int i = 0; i < 2; ++i) {
    float* dst = pq + ((size_t)ep * 64 + chalf * 32 + ty * 2 + i) * 1024 + n0 + tx * 4;
#pragma unroll
    for (int j = 0; j < 4; ++j) dst[j] = acc[i][j];
  }
}

// ---------------- build Y (8192 x 2048, bf16): [relu(P+Q+be) | x2] ----------
__global__ __launch_bounds__(256) void k_build_y(const float* __restrict__ pq0,
                                                 const float* __restrict__ pq1,
                                                 const float* __restrict__ x2,
                                                 const float* __restrict__ be,
                                                 const int* __restrict__ cp,
                                                 const int* __restrict__ vis,
                                                 u16* __restrict__ Y) {
  const int t = threadIdx.x;
  for (int rr = 0; rr < 8; ++rr) {
    const int b = blockIdx.x * 8 + rr;
    const int e = vis[b];
    u16x8 o;
    if (t < 128) {
      const int c0 = cp[2 * b], c1 = cp[2 * b + 1];
      const size_t po = ((size_t)(e * 2) * 64 + c0) * 1024 + t * 8;
      const size_t qo = ((size_t)(e * 2 + 1) * 64 + c1) * 1024 + t * 8;
      const float* B = be + e * 1024 + t * 8;
#pragma unroll
      for (int i = 0; i < 8; ++i) {
        float v = pq0[po + i] + pq1[po + i] + pq0[qo + i] + pq1[qo + i] + B[i];
        o[i] = f2bf(v > 0.f ? v : 0.f);
      }
      *(u16x8*)(Y + (size_t)b * 2048 + t * 8) = o;
    } else {
      const float* X = x2 + (size_t)b * 1024 + (size_t)(t - 128) * 8;
#pragma unroll
      for (int i = 0; i < 8; ++i) o[i] = f2bf(X[i]);
      *(u16x8*)(Y + (size_t)b * 2048 + 1024 + (size_t)(t - 128) * 8) = o;
    }
  }
}

// ---------------- bf16 MFMA GEMM, 128x128 tile, BK=64 single-buffer ---------
// MODE 0: C = relu(acc + bias), plus per-(row,colblock) (sum,sumsq) partials
//         into sp[row*64+cb] for LN1 stats.
// MODE 1: no C store. v = relu(rs1*acc - rs1*m1*s1[c] + c1b[c]) (LN1 folded),
//         emits per-(row,cb) float4 partials (S, SS, D=sum v*gw3[c], 0) for
//         the fused LN2+dot(W3) final.
template <int MODE>
__global__ __launch_bounds__(256, 3) void k_gemm(const u16* __restrict__ A,
                                                 const u16* __restrict__ BT,
                                                 const float* __restrict__ bias,
                                                 const float2* __restrict__ stats,
                                                 const float* __restrict__ s1,
                                                 const float* __restrict__ c1b,
                                                 const float* __restrict__ gw3,
                                                 float2* __restrict__ sp_out,
                                                 float4* __restrict__ part,
                                                 u16* __restrict__ C,
                                                 int M, int N, int K) {
  __shared__ u16 As[128 * 64];   // 16 KB
  __shared__ u16 Bs[128 * 64];   // 16 KB
  const int tid = threadIdx.x;
  const int lane = tid & 63;
  const int wave = tid >> 6;

  // XCD supertile swizzle (round-robin dispatch: bid%8 = XCD).
  const int nx = gridDim.x, ny = gridDim.y;
  const int bid = blockIdx.y * nx + blockIdx.x;
  const int stripe = ny >> 3;
  const int xcd = bid & 7;
  const int loc = bid >> 3;
  const int panel = loc / (stripe * 4);
  const int rem = loc - panel * (stripe * 4);
  const int by = xcd * stripe + (rem >> 2);
  const int bx = panel * 4 + (rem & 3);
  const int tileN = bx * 128;
  const int tileM = by * 128;
  const int wm = wave & 1;
  const int wn = wave >> 1;

  f32x4v acc[4][4];
#pragma unroll
  for (int i = 0; i < 4; ++i)
#pragma unroll
    for (int j = 0; j < 4; ++j) acc[i][j] = (f32x4v){0.f, 0.f, 0.f, 0.f};

  // Staging: row = tid>>3 (0..31), physical 16B chunk = tid&7.
  // XOR swizzle: phys chunk holds logical chunk (tid&7)^(row&7).
  const int srow = tid >> 3;
  const int lchunk = (tid & 7) ^ (srow & 7);
  const u16* aptr = A + (size_t)(tileM + srow) * K + lchunk * 8;
  const u16* bptr = BT + (size_t)(tileN + srow) * K + lchunk * 8;
  u16* asp = As + tid * 8;
  u16* bsp = Bs + tid * 8;

  // Fragment reads: row r, logical chunk c at phys c^(r&7); conflict-free.
  const int s = lane & 7;
  const int kp0 = ((lane >> 4) ^ s) * 8;
  const int kp1 = kp0 ^ 32;
  const int am = wm * 64 + (lane & 15);
  const int bn = wn * 64 + (lane & 15);

  for (int k0 = 0; k0 < K; k0 += 64) {
    G2L16(aptr, asp);
    G2L16(aptr + (size_t)32 * K, asp + 2048);
    G2L16(aptr + (size_t)64 * K, asp + 4096);
    G2L16(aptr + (size_t)96 * K, asp + 6144);
    G2L16(bptr, bsp);
    G2L16(bptr + (size_t)32 * K, bsp + 2048);
    G2L16(bptr + (size_t)64 * K, bsp + 4096);
    G2L16(bptr + (size_t)96 * K, bsp + 6144);
    aptr += 64;
    bptr += 64;
    __syncthreads();

    bf16x8 af[4], bfr[4];
#pragma unroll
    for (int mi = 0; mi < 4; ++mi)
      af[mi] = *(const bf16x8*)(As + (am + mi * 16) * 64 + kp0);
#pragma unroll
    for (int ni = 0; ni < 4; ++ni)
      bfr[ni] = *(const bf16x8*)(Bs + (bn + ni * 16) * 64 + kp0);
#pragma unroll
    for (int mi = 0; mi < 4; ++mi)
#pragma unroll
      for (int ni = 0; ni < 4; ++ni)
        acc[mi][ni] = __builtin_amdgcn_mfma_f32_16x16x32_bf16(af[mi], bfr[ni], acc[mi][ni], 0, 0, 0);
#pragma unroll
    for (int mi = 0; mi < 4; ++mi)
      af[mi] = *(const bf16x8*)(As + (am + mi * 16) * 64 + kp1);
#pragma unroll
    for (int ni = 0; ni < 4; ++ni)
      bfr[ni] = *(const bf16x8*)(Bs + (bn + ni * 16) * 64 + kp1);
#pragma unroll
    for (int mi = 0; mi < 4; ++mi)
#pragma unroll
      for (int ni = 0; ni < 4; ++ni)
        acc[mi][ni] = __builtin_amdgcn_mfma_f32_16x16x32_bf16(af[mi], bfr[ni], acc[mi][ni], 0, 0, 0);
    __syncthreads();
  }

  // C/D layout (m89-verified): col = lane&15, row = (lane>>4)*4 + reg
  const int crow = tileM + wm * 64 + (lane >> 4) * 4;
  const int ccol = tileN + wn * 64 + (lane & 15);
  float cv0[4], cv1[4], cg[4];
#pragma unroll
  for (int ni = 0; ni < 4; ++ni) {
    const int c = ccol + ni * 16;
    if (MODE == 0) {
      cv0[ni] = bias[c];
    } else {
      cv0[ni] = s1[c];
      cv1[ni] = c1b[c];
      cg[ni] = gw3[c];
    }
  }
  const int cb = bx * 2 + wn;  // col-block: [0,64) GEMM1, [0,32) GEMM2
#pragma unroll
  for (int mi = 0; mi < 4; ++mi) {
#pragma unroll
    for (int r = 0; r < 4; ++r) {
      const int row = crow + mi * 16 + r;
      if (MODE == 0) {
        float s_ = 0.f, ss_ = 0.f;
#pragma unroll
        for (int ni = 0; ni < 4; ++ni) {
          float v = acc[mi][ni][r] + cv0[ni];
          v = v > 0.f ? v : 0.f;
          s_ += v; ss_ += v * v;
          C[(size_t)row * N + ccol + ni * 16] = f2bf(v);
        }
#pragma unroll
        for (int off = 8; off >= 1; off >>= 1) {
          s_ += __shfl_xor(s_, off, 16);
          ss_ += __shfl_xor(ss_, off, 16);
        }
        if ((lane & 15) == 0)
          sp_out[(size_t)row * 64 + cb] = make_float2(s_, ss_);
      } else {
        float2 st = stats[row];
        const float m = st.x, rs = st.y;
        float s_ = 0.f, ss_ = 0.f, d_ = 0.f;
#pragma unroll
        for (int ni = 0; ni < 4; ++ni) {
          float v = rs * acc[mi][ni][r] - rs * m * cv0[ni] + cv1[ni];
          v = v > 0.f ? v : 0.f;
          s_ += v; ss_ += v * v; d_ += v * cg[ni];
        }
#pragma unroll
        for (int off = 8; off >= 1; off >>= 1) {
          s_ += __shfl_xor(s_, off, 16);
          ss_ += __shfl_xor(ss_, off, 16);
          d_ += __shfl_xor(d_, off, 16);
        }
        if ((lane & 15) == 0)
          part[(size_t)row * 32 + cb] = make_float4(s_, ss_, d_, 0.f);
      }
    }
  }
}

// ---- reduce: LN1 stats (coalesced sp), s1/c1b, gw3=g2*W3, SG/CB scalars ----
__global__ __launch_bounds__(256) void k_reduce(const float2* __restrict__ sp,
                                                float2* __restrict__ stats,
                                                const float* __restrict__ w2ps,
                                                const float* __restrict__ w2pc,
                                                const float* __restrict__ b2,
                                                float* __restrict__ s1,
                                                float* __restrict__ c1b,
                                                const float* __restrict__ g2,
                                                const float* __restrict__ bt2,
                                                const float* __restrict__ W3,
                                                float* __restrict__ gw3,
                                                float* __restrict__ scal) {
  __shared__ float red[8];
  const int bid = blockIdx.x;
  const int t = threadIdx.x;
  if (bid < 32) {
    const int g = t >> 4, l = t & 15;
#pragma unroll 1
    for (int rr = 0; rr < 16; ++rr) {
      const int row = bid * 256 + rr * 16 + g;
      float s = 0.f, ss = 0.f;
#pragma unroll
      for (int i = 0; i < 4; ++i) {
        float2 p = sp[(size_t)row * 64 + l * 4 + i];
        s += p.x; ss += p.y;
      }
#pragma unroll
      for (int off = 8; off >= 1; off >>= 1) {
        s += __shfl_xor(s, off, 16);
        ss += __shfl_xor(ss, off, 16);
      }
      if (l == 0) {
        float m = s * (1.f / 4096.f);
        float var = ss * (1.f / 4096.f) - m * m;
        stats[row] = make_float2(m, rsqrtf(var + 1e-5f));
      }
    }
  } else if (bid < 40) {
    const int nn = (bid - 32) * 256 + t;
    float s = 0.f, c = 0.f;
    for (int kb = 0; kb < 64; ++kb) {
      s += w2ps[(size_t)kb * 2048 + nn];
      c += w2pc[(size_t)kb * 2048 + nn];
    }
    s1[nn] = s;
    c1b[nn] = c + b2[nn];
  } else {
    // gw3[c] = g2[c]*W3[c]; SG = sum gw3; CB = sum bt2*W3
    float sg = 0.f, cb = 0.f;
    for (int i = 0; i < 8; ++i) {
      int c = i * 256 + t;
      float w3 = W3[c];
      float gv = g2[c] * w3;
      gw3[c] = gv;
      sg += gv;
      cb += bt2[c] * w3;
    }
#pragma unroll
    for (int off = 32; off > 0; off >>= 1) {
      sg += __shfl_down(sg, off, 64);
      cb += __shfl_down(cb, off, 64);
    }
    const int lane = t & 63, wv = t >> 6;
    if (lane == 0) { red[wv] = sg; red[4 + wv] = cb; }
    __syncthreads();
    if (t == 0) {
      scal[0] = red[0] + red[1] + red[2] + red[3];
      scal[1] = red[4] + red[5] + red[6] + red[7];
    }
  }
}

// ------- final: out[row] = sigmoid(rs*D - rs*m*SG + CB + b3) ----------------
__global__ __launch_bounds__(256) void k_final(const float4* __restrict__ part,
                                               const float* __restrict__ scal,
                                               const float* __restrict__ b3,
                                               float* __restrict__ out) {
  const int t = threadIdx.x;
  const int g = t >> 4, l = t & 15;
  const int row = blockIdx.x * 16 + g;
  float4 a = part[(size_t)row * 32 + l * 2];
  float4 b = part[(size_t)row * 32 + l * 2 + 1];
  float S = a.x + b.x, SS = a.y + b.y, D = a.z + b.z;
#pragma unroll
  for (int off = 8; off >= 1; off >>= 1) {
    S += __shfl_xor(S, off, 16);
    SS += __shfl_xor(SS, off, 16);
    D += __shfl_xor(D, off, 16);
  }
  if (l == 0) {
    float m = S * (1.f / 2048.f);
    float rs = rsqrtf(SS * (1.f / 2048.f) - m * m + 1e-5f);
    float logit = rs * D - rs * m * scal[0] + scal[1] + b3[0];
    out[row] = 1.f / (1.f + expf(-logit));
  }
}

extern "C" void kernel_launch(void* const* d_in, const int* in_sizes, int n_in,
                              void* d_out, int out_size, void* d_ws, size_t ws_size,
                              hipStream_t stream) {
  const float* x1 = (const float*)d_in[0];
  const float* x2 = (const float*)d_in[1];
  const float* We = (const float*)d_in[2];
  const float* be = (const float*)d_in[3];
  const float* W1 = (const float*)d_in[4];
  const float* b1 = (const float*)d_in[5];
  const float* g1 = (const float*)d_in[6];
  const float* bt1 = (const float*)d_in[7];
  const float* W2 = (const float*)d_in[8];
  const float* b2 = (const float*)d_in[9];
  const float* g2 = (const float*)d_in[10];
  const float* bt2 = (const float*)d_in[11];
  const float* W3 = (const float*)d_in[12];
  const float* b3 = (const float*)d_in[13];
  const int* cp = (const int*)d_in[14];
  const int* vis = (const int*)d_in[15];
  float* out = (float*)d_out;

  char* ws = (char*)d_ws;
  u16* W1T  = (u16*)(ws);                  // 4096x2048 bf16 = 16 MiB
  u16* W2gT = (u16*)(ws + 16777216);       // 2048x4096 bf16 = 16 MiB
  u16* Y    = (u16*)(ws + 33554432);       // 8192x2048 bf16 = 32 MiB
  u16* H1   = (u16*)(ws + 67108864);       // 8192x4096 bf16 = 64 MiB
  float* PQ0 = (float*)(ws + 134217728);   // 2 MiB
  float* PQ1 = (float*)(ws + 136314880);   // 2 MiB
  // sp (LN1 partials, 8192x64 float2 = 4 MiB) reuses PQ region (dead after
  // build_y); part (8192x32 float4 = 4 MiB) reuses it again after k_reduce.
  float2* sp = (float2*)(ws + 134217728);
  float4* part = (float4*)(ws + 134217728);
  float2* stats = (float2*)(ws + 138412032);  // 64 KiB
  float* s1   = (float*)(ws + 138477568);     // 8 KiB
  float* c1b  = (float*)(ws + 138485760);     // 8 KiB
  float* w2ps = (float*)(ws + 138493952);     // 64x2048 f32 = 512 KiB
  float* w2pc = (float*)(ws + 139018240);     // 512 KiB
  float* gw3  = (float*)(ws + 139542528);     // 8 KiB
  float* scal = (float*)(ws + 139550720);     // 2 f32

  k_transpose2<<<4096, 256, 0, stream>>>(W1, W1T, W2, W2gT, g1, bt1, w2ps, w2pc);
  k_pq<<<dim3(16, 8, 4), 256, 0, stream>>>(x1, We, PQ0, PQ1);
  k_build_y<<<1024, 256, 0, stream>>>(PQ0, PQ1, x2, be, cp, vis, Y);
  k_gemm<0><<<dim3(32, 64), 256, 0, stream>>>(
      Y, W1T, b1, nullptr, nullptr, nullptr, nullptr, sp, nullptr, H1,
      8192, 4096, 2048);
  k_reduce<<<41, 256, 0, stream>>>(sp, stats, w2ps, w2pc, b2, s1, c1b,
                                   g2, bt2, W3, gw3, scal);
  k_gemm<1><<<dim3(16, 64), 256, 0, stream>>>(
      H1, W2gT, nullptr, stats, s1, c1b, gw3, nullptr, part, nullptr,
      8192, 2048, 4096);
  k_final<<<512, 256, 0, stream>>>(part, scal, b3, out);
}